// Round 1
// baseline (1404.620 us; speedup 1.0000x reference)
//
#include <hip/hip_runtime.h>

#define T_TOK 4096
#define H_DIM 2048
#define I_DIM 5632
#define NE 8

typedef _Float16 f16;
typedef _Float16 f16x8 __attribute__((ext_vector_type(8)));
typedef _Float16 f16x4 __attribute__((ext_vector_type(4)));
typedef float f32x4 __attribute__((ext_vector_type(4)));

// ---- workspace layout (byte offsets) ----
#define OFF_META   0                         // counts[8] | offs[8] | cursor[8]
#define OFF_BTOK   256
#define OFF_BW     (256 + 32768)
#define OFF_RE     (256 + 2 * 32768)
#define OFF_RW     (256 + 3 * 32768)
#define OFF_HSB    (256 + 4 * 32768)
#define OFF_HB     (OFF_HSB + (size_t)T_TOK * H_DIM * 2)

// 16-byte-slot XOR swizzle within a 64-byte LDS row (4 slots): 8-way -> 4-way conflict
__device__ __forceinline__ int swz(int row, int bir) {
    return (bir & 15) | ((((bir >> 4) ^ row) & 3) << 4);
}

// ---------------- hs f32 -> f16 ----------------
__global__ void cvt_hs_kernel(const float* __restrict__ hs, f16* __restrict__ hsb) {
    size_t i = ((size_t)blockIdx.x * 256 + threadIdx.x) * 8;
    float4 a = *(const float4*)(hs + i);
    float4 b = *(const float4*)(hs + i + 4);
    f16x8 v;
    v[0] = (f16)a.x; v[1] = (f16)a.y; v[2] = (f16)a.z; v[3] = (f16)a.w;
    v[4] = (f16)b.x; v[5] = (f16)b.y; v[6] = (f16)b.z; v[7] = (f16)b.w;
    *(f16x8*)(hsb + i) = v;
}

// ---------------- gating: logits, softmax-top2, histogram ----------------
__global__ void gate_kernel(const float* __restrict__ hs, const float* __restrict__ gw,
                            int* __restrict__ re, float* __restrict__ rw,
                            int* __restrict__ counts) {
    int lane = threadIdx.x & 63;
    int t = blockIdx.x * 4 + (threadIdx.x >> 6);
    float acc[NE];
#pragma unroll
    for (int e = 0; e < NE; ++e) acc[e] = 0.f;
    const float* x = hs + (size_t)t * H_DIM;
    for (int i = lane; i < H_DIM; i += 64) {
        float xv = x[i];
#pragma unroll
        for (int e = 0; e < NE; ++e) acc[e] += xv * gw[e * H_DIM + i];
    }
#pragma unroll
    for (int e = 0; e < NE; ++e)
        for (int off = 32; off > 0; off >>= 1) acc[e] += __shfl_xor(acc[e], off);
    if (lane == 0) {
        int i1 = 0; float l1 = acc[0];
#pragma unroll
        for (int e = 1; e < NE; ++e) if (acc[e] > l1) { l1 = acc[e]; i1 = e; }
        int i2 = -1; float l2 = -1e30f;
#pragma unroll
        for (int e = 0; e < NE; ++e) if (e != i1 && acc[e] > l2) { l2 = acc[e]; i2 = e; }
        float aa = __expf(l2 - l1);             // <= 1
        float s = 1.f / (1.f + aa);
        re[t * 2] = i1; re[t * 2 + 1] = i2;
        rw[t * 2] = s;  rw[t * 2 + 1] = aa * s; // normalized top-2 softmax weights
        atomicAdd(&counts[i1], 1);
        atomicAdd(&counts[i2], 1);
    }
}

__global__ void scan_kernel(int* __restrict__ meta) {
    if (threadIdx.x == 0) {
        int s = 0;
        for (int e = 0; e < NE; ++e) { meta[8 + e] = s; meta[16 + e] = s; s += meta[e]; }
    }
}

__global__ void place_kernel(const int* __restrict__ re, const float* __restrict__ rw,
                             int* __restrict__ cursor, int* __restrict__ btok,
                             float* __restrict__ bwv) {
    int t = blockIdx.x * 256 + threadIdx.x;
    if (t >= T_TOK) return;
#pragma unroll
    for (int s = 0; s < 2; ++s) {
        int e = re[t * 2 + s];
        int p = atomicAdd(&cursor[e], 1);
        btok[p] = t;
        bwv[p] = rw[t * 2 + s];
    }
}

// ---------------- GEMM1: h = silu(X@Wg^T) * (X@Wu^T), X gathered rows ----------------
// block: 128 rows x 64 h-cols (g-tile + u-tile), BK=32, 4 waves (2x2), wave = 64x32
__global__ __launch_bounds__(256) void gemm1_kernel(
    const float* __restrict__ w13, const f16* __restrict__ hsb, f16* __restrict__ hb,
    const int* __restrict__ counts, const int* __restrict__ offs,
    const int* __restrict__ btok, int e_arg, int global_h)
{
    const int e = (e_arg >= 0) ? e_arg : (int)blockIdx.z;
    const int n_e = counts[e];
    const int by = blockIdx.y;
    if (by * 128 >= n_e) return;
    const int boff = offs[e];
    const int bx = blockIdx.x;
    const float* We = w13 + (size_t)e * (2 * I_DIM) * H_DIM;

    const int tid = threadIdx.x;
    const int lane = tid & 63;
    const int wid = tid >> 6;
    const int wm = wid >> 1, wn = wid & 1;

    __shared__ f16 As[128 * 32];
    __shared__ f16 Bgs[64 * 32];
    __shared__ f16 Bus[64 * 32];
    char* AsB = (char*)As; char* BgB = (char*)Bgs; char* BuB = (char*)Bus;

    // A gather sources: chunk c = i*256+tid covers row c/4, k-cols (c&3)*8..+7
    const f16* gA[2];
#pragma unroll
    for (int i = 0; i < 2; ++i) {
        int c = i * 256 + tid;
        int r = c >> 2;
        int idx = by * 128 + r;
        idx = idx < n_e ? idx : (n_e - 1);
        int tok = btok[boff + idx];
        gA[i] = hsb + (size_t)tok * H_DIM + (c & 3) * 8;
    }
    const float* gBg[2]; const float* gBu[2];
#pragma unroll
    for (int j = 0; j < 2; ++j) {
        int lin = j * 256 + tid;
        int r = lin >> 3;
        int k = (lin & 7) * 4;
        gBg[j] = We + (size_t)(bx * 64 + r) * H_DIM + k;
        gBu[j] = We + (size_t)(I_DIM + bx * 64 + r) * H_DIM + k;
    }

    f32x4 accg[4][2], accu[4][2];
#pragma unroll
    for (int m = 0; m < 4; ++m)
#pragma unroll
        for (int n = 0; n < 2; ++n) { accg[m][n] = (f32x4)0.f; accu[m][n] = (f32x4)0.f; }

    const int NT = H_DIM / 32;
    f16x8 av0, av1; float4 bg0, bg1, bu0, bu1;
    // prologue load tile 0
    av0 = *(const f16x8*)(gA[0]); av1 = *(const f16x8*)(gA[1]);
    bg0 = *(const float4*)(gBg[0]); bg1 = *(const float4*)(gBg[1]);
    bu0 = *(const float4*)(gBu[0]); bu1 = *(const float4*)(gBu[1]);

    for (int kt = 0; kt < NT; ++kt) {
        __syncthreads();
        // write staged regs -> LDS (swizzled)
        {
            int c = tid;               int r = c >> 2;
            *(f16x8*)(AsB + r * 64 + swz(r, (c & 3) * 16)) = av0;
            c = 256 + tid;             r = c >> 2;
            *(f16x8*)(AsB + r * 64 + swz(r, (c & 3) * 16)) = av1;
        }
#pragma unroll
        for (int j = 0; j < 2; ++j) {
            int lin = j * 256 + tid; int r = lin >> 3; int bir = (lin & 7) * 8;
            float4 bg = j ? bg1 : bg0;
            float4 bu = j ? bu1 : bu0;
            f16x4 g4, u4;
            g4[0] = (f16)bg.x; g4[1] = (f16)bg.y; g4[2] = (f16)bg.z; g4[3] = (f16)bg.w;
            u4[0] = (f16)bu.x; u4[1] = (f16)bu.y; u4[2] = (f16)bu.z; u4[3] = (f16)bu.w;
            *(f16x4*)(BgB + r * 64 + swz(r, bir)) = g4;
            *(f16x4*)(BuB + r * 64 + swz(r, bir)) = u4;
        }
        __syncthreads();
        // prefetch next tile while computing this one
        if (kt + 1 < NT) {
            int k0 = (kt + 1) * 32;
            av0 = *(const f16x8*)(gA[0] + k0); av1 = *(const f16x8*)(gA[1] + k0);
            bg0 = *(const float4*)(gBg[0] + k0); bg1 = *(const float4*)(gBg[1] + k0);
            bu0 = *(const float4*)(gBu[0] + k0); bu1 = *(const float4*)(gBu[1] + k0);
        }
        f16x8 a[4], bgf[2], buf_[2];
        const int kb = (lane >> 4) * 16;
#pragma unroll
        for (int m = 0; m < 4; ++m) {
            int r = wm * 64 + m * 16 + (lane & 15);
            a[m] = *(const f16x8*)(AsB + r * 64 + swz(r, kb));
        }
#pragma unroll
        for (int n = 0; n < 2; ++n) {
            int r = wn * 32 + n * 16 + (lane & 15);
            bgf[n]  = *(const f16x8*)(BgB + r * 64 + swz(r, kb));
            buf_[n] = *(const f16x8*)(BuB + r * 64 + swz(r, kb));
        }
#pragma unroll
        for (int m = 0; m < 4; ++m)
#pragma unroll
            for (int n = 0; n < 2; ++n) {
                accg[m][n] = __builtin_amdgcn_mfma_f32_16x16x32_f16(a[m], bgf[n],  accg[m][n], 0, 0, 0);
                accu[m][n] = __builtin_amdgcn_mfma_f32_16x16x32_f16(a[m], buf_[n], accu[m][n], 0, 0, 0);
            }
    }
    // epilogue: silu(g)*u -> f16 h
    const int hbase = (global_h ? boff : 0) + by * 128;
#pragma unroll
    for (int m = 0; m < 4; ++m) {
        int rl0 = wm * 64 + m * 16 + ((lane >> 4) << 2);
#pragma unroll
        for (int r = 0; r < 4; ++r) {
            int rl = rl0 + r;
            if (by * 128 + rl < n_e) {
#pragma unroll
                for (int n = 0; n < 2; ++n) {
                    float g = accg[m][n][r];
                    float u = accu[m][n][r];
                    float h = g / (1.f + __expf(-g)) * u;
                    hb[(size_t)(hbase + rl) * I_DIM + bx * 64 + wn * 32 + n * 16 + (lane & 15)] = (f16)h;
                }
            }
        }
    }
}

// ---------------- GEMM2: out[tok] += w * (h @ w2^T) ----------------
// block: 128 rows x 128 out-cols, BK=32, 4 waves (2x2), wave = 64x64
__global__ __launch_bounds__(256) void gemm2_kernel(
    const float* __restrict__ w2, const f16* __restrict__ hb, float* __restrict__ out,
    const int* __restrict__ counts, const int* __restrict__ offs,
    const int* __restrict__ btok, const float* __restrict__ bwv, int e_arg, int global_h)
{
    const int e = (e_arg >= 0) ? e_arg : (int)blockIdx.z;
    const int n_e = counts[e];
    const int by = blockIdx.y;
    if (by * 128 >= n_e) return;
    const int boff = offs[e];
    const int bx = blockIdx.x;
    const float* We = w2 + (size_t)e * H_DIM * I_DIM;

    const int tid = threadIdx.x;
    const int lane = tid & 63;
    const int wid = tid >> 6;
    const int wm = wid >> 1, wn = wid & 1;

    __shared__ f16 As[128 * 32];
    __shared__ f16 Bs[128 * 32];
    char* AsB = (char*)As; char* BsB = (char*)Bs;

    const int hbase = (global_h ? boff : 0) + by * 128;
    const f16* gA[2];
#pragma unroll
    for (int i = 0; i < 2; ++i) {
        int c = i * 256 + tid;
        int r = c >> 2;
        gA[i] = hb + (size_t)(hbase + r) * I_DIM + (c & 3) * 8;
    }
    const float* gB[4];
#pragma unroll
    for (int j = 0; j < 4; ++j) {
        int lin = j * 256 + tid;
        int r = lin >> 3;
        int k = (lin & 7) * 4;
        gB[j] = We + (size_t)(bx * 128 + r) * I_DIM + k;
    }

    f32x4 acc[4][4];
#pragma unroll
    for (int m = 0; m < 4; ++m)
#pragma unroll
        for (int n = 0; n < 4; ++n) acc[m][n] = (f32x4)0.f;

    const int NT = I_DIM / 32;
    f16x8 av0, av1; float4 bv0, bv1, bv2, bv3;
    av0 = *(const f16x8*)(gA[0]); av1 = *(const f16x8*)(gA[1]);
    bv0 = *(const float4*)(gB[0]); bv1 = *(const float4*)(gB[1]);
    bv2 = *(const float4*)(gB[2]); bv3 = *(const float4*)(gB[3]);

    for (int kt = 0; kt < NT; ++kt) {
        __syncthreads();
        {
            int c = tid;       int r = c >> 2;
            *(f16x8*)(AsB + r * 64 + swz(r, (c & 3) * 16)) = av0;
            c = 256 + tid;     r = c >> 2;
            *(f16x8*)(AsB + r * 64 + swz(r, (c & 3) * 16)) = av1;
        }
#pragma unroll
        for (int j = 0; j < 4; ++j) {
            int lin = j * 256 + tid; int r = lin >> 3; int bir = (lin & 7) * 8;
            float4 b = (j == 0) ? bv0 : (j == 1) ? bv1 : (j == 2) ? bv2 : bv3;
            f16x4 b4;
            b4[0] = (f16)b.x; b4[1] = (f16)b.y; b4[2] = (f16)b.z; b4[3] = (f16)b.w;
            *(f16x4*)(BsB + r * 64 + swz(r, bir)) = b4;
        }
        __syncthreads();
        if (kt + 1 < NT) {
            int k0 = (kt + 1) * 32;
            av0 = *(const f16x8*)(gA[0] + k0); av1 = *(const f16x8*)(gA[1] + k0);
            bv0 = *(const float4*)(gB[0] + k0); bv1 = *(const float4*)(gB[1] + k0);
            bv2 = *(const float4*)(gB[2] + k0); bv3 = *(const float4*)(gB[3] + k0);
        }
        f16x8 a[4], b[4];
        const int kb = (lane >> 4) * 16;
#pragma unroll
        for (int m = 0; m < 4; ++m) {
            int r = wm * 64 + m * 16 + (lane & 15);
            a[m] = *(const f16x8*)(AsB + r * 64 + swz(r, kb));
        }
#pragma unroll
        for (int n = 0; n < 4; ++n) {
            int r = wn * 64 + n * 16 + (lane & 15);
            b[n] = *(const f16x8*)(BsB + r * 64 + swz(r, kb));
        }
#pragma unroll
        for (int m = 0; m < 4; ++m)
#pragma unroll
            for (int n = 0; n < 4; ++n)
                acc[m][n] = __builtin_amdgcn_mfma_f32_16x16x32_f16(a[m], b[n], acc[m][n], 0, 0, 0);
    }
    // epilogue: weighted scatter-add
#pragma unroll
    for (int m = 0; m < 4; ++m) {
        int rl0 = wm * 64 + m * 16 + ((lane >> 4) << 2);
#pragma unroll
        for (int r = 0; r < 4; ++r) {
            int rl = rl0 + r;
            if (by * 128 + rl < n_e) {
                int p = boff + by * 128 + rl;
                int tok = btok[p];
                float w = bwv[p];
#pragma unroll
                for (int n = 0; n < 4; ++n) {
                    atomicAdd(&out[(size_t)tok * H_DIM + bx * 128 + wn * 64 + n * 16 + (lane & 15)],
                              w * acc[m][n][r]);
                }
            }
        }
    }
}

extern "C" void kernel_launch(void* const* d_in, const int* in_sizes, int n_in,
                              void* d_out, int out_size, void* d_ws, size_t ws_size,
                              hipStream_t stream) {
    const float* hs  = (const float*)d_in[0];
    const float* gw  = (const float*)d_in[1];
    const float* w13 = (const float*)d_in[2];
    const float* w2  = (const float*)d_in[3];
    float* out = (float*)d_out;

    char* ws = (char*)d_ws;
    int*   meta = (int*)(ws + OFF_META);
    int*   btok = (int*)(ws + OFF_BTOK);
    float* bwv  = (float*)(ws + OFF_BW);
    int*   re   = (int*)(ws + OFF_RE);
    float* rw   = (float*)(ws + OFF_RW);
    f16*   hsb  = (f16*)(ws + OFF_HSB);
    f16*   hb   = (f16*)(ws + OFF_HB);

    hipMemsetAsync(d_out, 0, (size_t)T_TOK * H_DIM * 4, stream);
    hipMemsetAsync(meta, 0, 256, stream);

    cvt_hs_kernel<<<(T_TOK * H_DIM) / (256 * 8), 256, 0, stream>>>(hs, hsb);
    gate_kernel<<<T_TOK / 4, 256, 0, stream>>>(hs, gw, re, rw, meta);
    scan_kernel<<<1, 64, 0, stream>>>(meta);
    place_kernel<<<T_TOK / 256, 256, 0, stream>>>(re, rw, meta + 16, btok, bwv);

    size_t need_allpairs = OFF_HB + (size_t)(2 * T_TOK + 128) * I_DIM * 2;
    if (ws_size >= need_allpairs) {
        gemm1_kernel<<<dim3(I_DIM / 64, T_TOK / 128, NE), 256, 0, stream>>>(
            w13, hsb, hb, meta, meta + 8, btok, -1, 1);
        gemm2_kernel<<<dim3(H_DIM / 128, T_TOK / 128, NE), 256, 0, stream>>>(
            w2, hb, out, meta, meta + 8, btok, bwv, -1, 1);
    } else {
        // per-expert h-buffer reuse (smaller ws): 16 sequential gemm launches
        for (int e = 0; e < NE; ++e) {
            gemm1_kernel<<<dim3(I_DIM / 64, T_TOK / 128, 1), 256, 0, stream>>>(
                w13, hsb, hb, meta, meta + 8, btok, e, 0);
            gemm2_kernel<<<dim3(H_DIM / 128, T_TOK / 128, 1), 256, 0, stream>>>(
                w2, hb, out, meta, meta + 8, btok, bwv, e, 0);
        }
    }
}